// Round 1
// 206.313 us; speedup vs baseline: 1.0034x; 1.0034x over previous
//
#include <hip/hip_runtime.h>

// ClusterDiceLoss: segmented dice over 64 clusters of a 256^3 volume.
// Memory floor: 201 MB read -> ~32 us at 6.3 TB/s (less when L3-resident).
// R1 (115 us): latency-bound. R2 (432 us): 8MB-stride batching aliased channels.
// R3 (76 us kernel): VALUBusy 5%, HBM 17%, occupancy 50% -> stall-bound.
//   Diagnosis: (a) wave64 u64 LDS atomics into one 65-slot histogram = 16
//   bank-pairs + same-address RMW serialization on the shared DS pipe;
//   (b) VGPR_Count=36 proves the 12-load window was compiler-collapsed to ~5.
// R4: u32 packed atomics into per-16-lane replicated histograms (16 copies,
//   all-32-bank spread, ~2-way max same-address), full unroll x8 with
//   __launch_bounds__(256,4) so all 24 loads are truly in flight.

#define NSEG 65          // clusters 0..64 (0 = background, dropped at finalize)
#define NWAVES 4         // 256 threads / wave64
#define NSUB 4           // histogram copies per wave (one per 16-lane group)
#define NCOPY (NWAVES * NSUB)   // 16 copies per block
#define BLOCKS 2048
#define THREADS 256
#define UNROLL 8

// Per-element u32 contribution: inter<<20 | sum_p<<10 | sum_t.
// Field bound: one copy is shared by 16 lanes x 32 elements/thread = 512 max
// per segment < 1023, so 10-bit fields never carry. (Valid while per-thread
// element count <= 63, i.e. n <= ~125M; here n = 16.7M -> 32.)
__device__ __forceinline__ unsigned int pack32(float p, float t) {
    unsigned int sp = (p != 0.0f) ? 1u : 0u;
    unsigned int st = (t != 0.0f) ? 1u : 0u;
    return ((sp & st) << 20) | (sp << 10) | st;
}

__device__ __forceinline__ void accum4(unsigned int (*s_cnt)[NSEG], int copy,
                                       float4 p, float4 t, int4 l) {
    atomicAdd(&s_cnt[copy][l.x], pack32(p.x, t.x));
    atomicAdd(&s_cnt[copy][l.y], pack32(p.y, t.y));
    atomicAdd(&s_cnt[copy][l.z], pack32(p.z, t.z));
    atomicAdd(&s_cnt[copy][l.w], pack32(p.w, t.w));
}

__global__ __launch_bounds__(THREADS, 4) void seg_count_kernel(
    const float* __restrict__ pred,
    const float* __restrict__ target,
    const int* __restrict__ labels,
    unsigned long long* __restrict__ g_counts,   // [NSEG] packed u64, pre-zeroed
    int n)
{
    // 16 copies x 65 u32 = 4160 B. Copy c, segment s sits at word (c*65+s),
    // bank = (c*65+s)%32 = (c+s)%32 -> random s covers all 32 banks and the
    // 4 copies of a wave are mutually offset. Same-address collisions occur
    // only within a 16-lane group over 65 bins (expected max ~2).
    __shared__ unsigned int s_cnt[NCOPY][NSEG];
    const int tid = threadIdx.x;
    const int copy = tid >> 4;

    for (int i = tid; i < NCOPY * NSEG; i += THREADS)
        ((unsigned int*)s_cnt)[i] = 0u;
    __syncthreads();

    const int n_vec = n >> 2;  // float4 groups
    const float4* __restrict__ p4 = (const float4*)pred;
    const float4* __restrict__ t4 = (const float4*)target;
    const int4*   __restrict__ l4 = (const int4*)labels;

    // contiguous chunk per block; for n=256^3 every thread runs the unrolled
    // body exactly once (chunk = 2048 = UNROLL*THREADS).
    const int chunk = (n_vec + (int)gridDim.x - 1) / (int)gridDim.x;
    const int base = blockIdx.x * chunk;
    const int end = min(base + chunk, n_vec);

    int idx = base + tid;
    for (; idx + (UNROLL - 1) * THREADS < end; idx += UNROLL * THREADS) {
        float4 p[UNROLL]; float4 t[UNROLL]; int4 l[UNROLL];
        #pragma unroll
        for (int u = 0; u < UNROLL; ++u) p[u] = p4[idx + u * THREADS];
        #pragma unroll
        for (int u = 0; u < UNROLL; ++u) t[u] = t4[idx + u * THREADS];
        #pragma unroll
        for (int u = 0; u < UNROLL; ++u) l[u] = l4[idx + u * THREADS];
        #pragma unroll
        for (int u = 0; u < UNROLL; ++u) accum4(s_cnt, copy, p[u], t[u], l[u]);
    }
    for (; idx < end; idx += THREADS)
        accum4(s_cnt, copy, p4[idx], t4[idx], l4[idx]);

    // scalar tail (n not divisible by 4): block 0 only
    if (blockIdx.x == 0) {
        for (int i = (n_vec << 2) + tid; i < n; i += THREADS)
            atomicAdd(&s_cnt[copy][labels[i]], pack32(pred[i], target[i]));
    }
    __syncthreads();

    // fold the 16 u32 copies -> one packed u64 global atomic per segment.
    // Per-block field sums <= 16*1023 = 16368 < 2^21, so u64 fields are safe.
    for (int s = tid; s < NSEG; s += THREADS) {
        unsigned long long in = 0, sp = 0, st = 0;
        #pragma unroll
        for (int c = 0; c < NCOPY; ++c) {
            unsigned int v = s_cnt[c][s];
            st += v & 0x3FFu;
            sp += (v >> 10) & 0x3FFu;
            in += v >> 20;
        }
        unsigned long long tot = (in << 42) | (sp << 21) | st;
        if (tot) atomicAdd(&g_counts[s], tot);
    }
}

__global__ __launch_bounds__(64) void dice_finalize_kernel(
    const unsigned long long* __restrict__ g_counts,
    const int* __restrict__ nc_ptr,
    float* __restrict__ out)
{
    const int nc = *nc_ptr;          // 64
    const int tid = threadIdx.x;
    float local = 0.0f;
    for (int c = 1 + tid; c <= nc; c += 64) {
        unsigned long long v = g_counts[c];
        float in = (float)(v >> 42);
        float sp = (float)((v >> 21) & 0x1FFFFFull);
        float st = (float)(v & 0x1FFFFFull);
        float uni = sp + st;
        local += (uni > 0.0f) ? (2.0f * in / uni) : 1.0f;
    }
    #pragma unroll
    for (int off = 32; off > 0; off >>= 1)
        local += __shfl_down(local, off);
    if (tid == 0) out[0] = 1.0f - local / (float)nc;
}

extern "C" void kernel_launch(void* const* d_in, const int* in_sizes, int n_in,
                              void* d_out, int out_size, void* d_ws, size_t ws_size,
                              hipStream_t stream) {
    const float* pred   = (const float*)d_in[0];
    const float* target = (const float*)d_in[1];
    const int*   labels = (const int*)d_in[2];
    const int*   nc_ptr = (const int*)d_in[3];
    float* out = (float*)d_out;
    unsigned long long* g_counts = (unsigned long long*)d_ws;

    const int n = in_sizes[0];

    hipMemsetAsync(d_ws, 0, NSEG * sizeof(unsigned long long), stream);

    seg_count_kernel<<<BLOCKS, THREADS, 0, stream>>>(
        pred, target, labels, g_counts, n);
    dice_finalize_kernel<<<1, 64, 0, stream>>>(g_counts, nc_ptr, out);
}

// Round 2
// 197.406 us; speedup vs baseline: 1.0487x; 1.0451x over previous
//
#include <hip/hip_runtime.h>

// ClusterDiceLoss: segmented dice over 64 clusters of a 256^3 volume.
// Memory floor: 201 MB read -> ~32 us at 6.3 TB/s (less when L3-resident).
// R1 (115 us): latency-bound. R2 (432 us): 8MB-stride batching aliased channels.
// R3 (76 us kernel): stall-bound, all pipes idle.
// R4 (78 us): LDS conflict fix (2.2M->1.3M) changed NOTHING -> LDS not the
//   bottleneck. Evidence for the real one:
//   (a) WRITE_SIZE 1088 KB == 2048 blocks x 65 segs x 8 B: the end-of-block
//       device-scope atomics all land in NINE cache lines -> ~15k serialized
//       same-line RMWs per line at the cross-XCD coherence point ~= 46 us.
//   (b) L3-warm replays (FETCH ~1 MB) run the SAME 76 us as HBM-fed runs ->
//       kernel is serialization-bound, not BW-bound.
// R5: (1) 64 replicated partial arrays part[65][64]; block atomics go to
//   replica blockIdx&63 -> per-address contention 2048->32, lines 9->520.
//   Finalize kernel folds the 33 KB (L2-resident) and computes dice.
//   (2) sched_barrier(0) between the 24 loads and the LDS atomics so the
//   compiler cannot collapse the load window again (VGPR 44 -> ~110).

#define NSEG 65          // clusters 0..64 (0 = background, dropped at finalize)
#define NREP 64          // replicated global partial arrays
#define REP_MASK 63
#define NWAVES 4         // 256 threads / wave64
#define NCOPY 16         // LDS histogram copies per block (one per 16 lanes)
#define BLOCKS 2048
#define THREADS 256
#define UNROLL 8

// Per-element u32 contribution: inter<<20 | sum_p<<10 | sum_t.
// One LDS copy covers 16 lanes x 32 elems = 512 max per segment < 1023,
// so 10-bit fields never carry.
__device__ __forceinline__ unsigned int pack32(float p, float t) {
    unsigned int sp = (p != 0.0f) ? 1u : 0u;
    unsigned int st = (t != 0.0f) ? 1u : 0u;
    return ((sp & st) << 20) | (sp << 10) | st;
}

__device__ __forceinline__ void accum4(unsigned int (*s_cnt)[NSEG], int copy,
                                       float4 p, float4 t, int4 l) {
    atomicAdd(&s_cnt[copy][l.x], pack32(p.x, t.x));
    atomicAdd(&s_cnt[copy][l.y], pack32(p.y, t.y));
    atomicAdd(&s_cnt[copy][l.z], pack32(p.z, t.z));
    atomicAdd(&s_cnt[copy][l.w], pack32(p.w, t.w));
}

__global__ __launch_bounds__(THREADS, 4) void seg_count_kernel(
    const float* __restrict__ pred,
    const float* __restrict__ target,
    const int* __restrict__ labels,
    unsigned long long* __restrict__ part,   // [NSEG][NREP] packed u64, zeroed
    int n)
{
    __shared__ unsigned int s_cnt[NCOPY][NSEG];
    const int tid = threadIdx.x;
    const int copy = tid >> 4;
    const int rep = (int)blockIdx.x & REP_MASK;

    for (int i = tid; i < NCOPY * NSEG; i += THREADS)
        ((unsigned int*)s_cnt)[i] = 0u;
    __syncthreads();

    const int n_vec = n >> 2;  // float4 groups
    const float4* __restrict__ p4 = (const float4*)pred;
    const float4* __restrict__ t4 = (const float4*)target;
    const int4*   __restrict__ l4 = (const int4*)labels;

    // contiguous chunk per block; for n=256^3 every thread runs the unrolled
    // body exactly once (chunk = 2048 = UNROLL*THREADS).
    const int chunk = (n_vec + (int)gridDim.x - 1) / (int)gridDim.x;
    const int base = blockIdx.x * chunk;
    const int end = min(base + chunk, n_vec);

    int idx = base + tid;
    for (; idx + (UNROLL - 1) * THREADS < end; idx += UNROLL * THREADS) {
        float4 p[UNROLL]; float4 t[UNROLL]; int4 l[UNROLL];
        #pragma unroll
        for (int u = 0; u < UNROLL; ++u) p[u] = p4[idx + u * THREADS];
        #pragma unroll
        for (int u = 0; u < UNROLL; ++u) t[u] = t4[idx + u * THREADS];
        #pragma unroll
        for (int u = 0; u < UNROLL; ++u) l[u] = l4[idx + u * THREADS];
        // Pin the window: no atomic may be hoisted above this point, so all
        // 24 loads are issued before the first s_waitcnt-consuming use.
        __builtin_amdgcn_sched_barrier(0);
        #pragma unroll
        for (int u = 0; u < UNROLL; ++u) accum4(s_cnt, copy, p[u], t[u], l[u]);
    }
    for (; idx < end; idx += THREADS)
        accum4(s_cnt, copy, p4[idx], t4[idx], l4[idx]);

    // scalar tail (n not divisible by 4): block 0 only
    if (blockIdx.x == 0) {
        for (int i = (n_vec << 2) + tid; i < n; i += THREADS)
            atomicAdd(&s_cnt[copy][labels[i]], pack32(pred[i], target[i]));
    }
    __syncthreads();

    // fold the 16 u32 copies -> one packed u64 global atomic per segment,
    // into this block's replica slice. Per-replica per-segment field sums
    // <= 32 blocks * 8192 = 262k < 2^21 -> no carry, guaranteed.
    for (int s = tid; s < NSEG; s += THREADS) {
        unsigned long long in = 0, sp = 0, st = 0;
        #pragma unroll
        for (int c = 0; c < NCOPY; ++c) {
            unsigned int v = s_cnt[c][s];
            st += v & 0x3FFu;
            sp += (v >> 10) & 0x3FFu;
            in += v >> 20;
        }
        unsigned long long tot = (in << 42) | (sp << 21) | st;
        if (tot) atomicAdd(&part[s * NREP + rep], tot);
    }
}

__global__ __launch_bounds__(256) void dice_finalize_kernel(
    const unsigned long long* __restrict__ part,   // [NSEG][NREP]
    const int* __restrict__ nc_ptr,
    float* __restrict__ out)
{
    const int nc = *nc_ptr;          // 64
    const int tid = threadIdx.x;
    // 4 threads per segment, segments 1..64 (segment 0 = background, dropped).
    const int s = 1 + (tid >> 2);
    const int q = tid & 3;

    unsigned long long acc = 0;
    const unsigned long long* row = part + s * NREP + q * 16;
    #pragma unroll
    for (int i = 0; i < 16; ++i) acc += row[i];
    // combine the 4 quarter-sums (adjacent lanes of the same wave)
    acc += __shfl_xor(acc, 1);
    acc += __shfl_xor(acc, 2);

    __shared__ float s_dice[64];
    if (q == 0) {
        float in = (float)(acc >> 42);
        float sp = (float)((acc >> 21) & 0x1FFFFFull);
        float st = (float)(acc & 0x1FFFFFull);
        float uni = sp + st;
        float dice = (uni > 0.0f) ? (2.0f * in / uni) : 1.0f;
        s_dice[s - 1] = (s <= nc) ? dice : 0.0f;
    }
    __syncthreads();

    if (tid < 64) {
        float local = s_dice[tid];
        #pragma unroll
        for (int off = 32; off > 0; off >>= 1)
            local += __shfl_down(local, off);
        if (tid == 0) out[0] = 1.0f - local / (float)nc;
    }
}

extern "C" void kernel_launch(void* const* d_in, const int* in_sizes, int n_in,
                              void* d_out, int out_size, void* d_ws, size_t ws_size,
                              hipStream_t stream) {
    const float* pred   = (const float*)d_in[0];
    const float* target = (const float*)d_in[1];
    const int*   labels = (const int*)d_in[2];
    const int*   nc_ptr = (const int*)d_in[3];
    float* out = (float*)d_out;
    unsigned long long* part = (unsigned long long*)d_ws;

    const int n = in_sizes[0];

    hipMemsetAsync(d_ws, 0, NSEG * NREP * sizeof(unsigned long long), stream);

    seg_count_kernel<<<BLOCKS, THREADS, 0, stream>>>(
        pred, target, labels, part, n);
    dice_finalize_kernel<<<1, 256, 0, stream>>>(part, nc_ptr, out);
}